// Round 7
// baseline (89.632 us; speedup 1.0000x reference)
//
#include <hip/hip_runtime.h>

#define NPART 4096
#define E_TOT 262144
#define HID   128
#define FDOF  6
#define BM    64                 // edges per block-iteration
#define NIT   (E_TOT / BM)       // 4096
#define GRID  1024               // 4 iters/block exactly (balanced)
#define XPAD  40                 // 80 B rows = 5x16 -> aligned b128 reads
#define HPAD  136                // 272 B rows = 17x16 -> aligned

typedef __bf16 bf16x8 __attribute__((ext_vector_type(8)));
typedef __bf16 bf16x4 __attribute__((ext_vector_type(4)));
typedef __bf16 bf16x2 __attribute__((ext_vector_type(2)));
typedef float  f32x4  __attribute__((ext_vector_type(4)));

__global__ void pairvel_zero_kernel(float* __restrict__ out, int n) {
    const int i = blockIdx.x * blockDim.x + threadIdx.x;
    if (i < n) out[i] = 0.0f;
}

// Round 7: TRANSPOSED GEMMs (D = W^T · X^T). Weights are the A-operand,
// activations the B-operand; D rows = hidden unit, cols = edge. Lane's 4
// accumulator elements are 4 CONSECUTIVE hidden cols of one edge row ->
// packed bf16x4 ds_write_b64 (16 writes/wave-iter vs 40 scalar b16).
// Features reordered (W1 rows permuted to match) so X staging packs into
// 7 vector LDS writes vs 19 scalar. Prefetch depth-1, issued at start of
// L2 phase (its forced vmcnt(0) drain at barrier C is covered by the 32-
// MFMA L2 phase — compiler drains vmcnt before EVERY s_barrier, so deeper
// prefetch is structurally useless at HIP level).
//
// New X feature layout (orig index -> new col): force_tgt 7..12 -> 0..5,
// force_src 13..18 -> 6..11, geometry 0..6 -> 12..18.  orig(k) = k<12 ?
// k+7 : k-12.
__global__ __launch_bounds__(256) void pairvel_mfma_kernel(
    const float* __restrict__ rel,       // [N,N,3]
    const int*   __restrict__ tgt,       // [E]
    const int*   __restrict__ src,       // [E]
    const float* __restrict__ force,     // [N,6]
    const float* __restrict__ visc,
    const float* __restrict__ medianp,
    const float* __restrict__ contactp,
    const float* __restrict__ W1,        // [19,128]
    const float* __restrict__ b1,        // [128]
    const float* __restrict__ W2,        // [128,128]
    const float* __restrict__ b2,        // [128]
    const float* __restrict__ W3,        // [128,6]
    const float* __restrict__ b3,        // [6]
    float* __restrict__ out)             // [N,6]
{
    const int tid = threadIdx.x;
    const int w   = tid >> 6;     // wave 0..3
    const int l   = tid & 63;     // lane
    const int l15 = l & 15;
    const int lhi = l >> 4;       // 0..3

    // ---- weight A-fragments: lane l holds A[row=l15+n0][k=lhi*8+r] = W[k][n]
    bf16x8 w1f[2], w2f[4][2], w3f[4];
    #pragma unroll
    for (int nb = 0; nb < 2; ++nb) {
        const int n = (2 * w + nb) * 16 + l15;
        #pragma unroll
        for (int r = 0; r < 8; ++r) {
            const int k = lhi * 8 + r;                  // new feature col
            const int ko = (k < 12) ? k + 7 : k - 12;   // orig feature idx
            w1f[nb][r] = (k < 19) ? (__bf16)W1[ko * HID + n] : (__bf16)0.0f;
        }
    }
    #pragma unroll
    for (int kt = 0; kt < 4; ++kt)
        #pragma unroll
        for (int nb = 0; nb < 2; ++nb) {
            const int n = (2 * w + nb) * 16 + l15;
            #pragma unroll
            for (int r = 0; r < 8; ++r)
                w2f[kt][nb][r] = (__bf16)W2[(kt * 32 + lhi * 8 + r) * HID + n];
        }
    #pragma unroll
    for (int kt = 0; kt < 4; ++kt)
        #pragma unroll
        for (int r = 0; r < 8; ++r) {
            const int k = kt * 32 + lhi * 8 + r;
            w3f[kt][r] = (l15 < FDOF) ? (__bf16)W3[k * FDOF + l15] : (__bf16)0.0f;
        }

    // bias init vectors: lane's 4 D-rows are n = n0 + lhi*4 + {0..3}
    f32x4 b1i[2], b2i[2];
    #pragma unroll
    for (int nb = 0; nb < 2; ++nb) {
        b1i[nb] = *reinterpret_cast<const f32x4*>(
            &b1[(2 * w + nb) * 16 + lhi * 4]);
        b2i[nb] = *reinterpret_cast<const f32x4*>(
            &b2[(2 * w + nb) * 16 + lhi * 4]);
    }
    float b3r[4];
    #pragma unroll
    for (int r = 0; r < 4; ++r) {
        const int d = lhi * 4 + r;
        b3r[r] = (d < FDOF) ? b3[d] : 0.0f;
    }
    const float inv_mu  = 1.0f / visc[0];
    const float median  = medianp[0];
    const float contact = contactp[0];

    __shared__ __align__(16) __bf16 Xs[2][BM][XPAD];   // 10240 B
    __shared__ __align__(16) __bf16 Hs[BM][HPAD];      // 17408 B (H1 then H2)
    __shared__ int tgts[2][BM];                        //   512 B

    // zero X pad cols 19..31 in both buffers once (32..39 never read)
    for (int t = tid; t < 2 * BM * 13; t += 256) {
        const int b = t / (BM * 13), rem = t % (BM * 13);
        Xs[b][rem / 13][19 + rem % 13] = (__bf16)0.0f;
    }

    // ---- per-thread prefetch state (8 scalars) -----------------------------
    int   p_i0 = 0;
    float p_v0 = 0.f, p_v1 = 0.f, p_v2 = 0.f;
    float p_f3 = 0.f, p_f4 = 0.f, p_f5 = 0.f;

    auto gather_load = [&](int e0n) {
        if (tid < BM) {                       // geometry
            const int eg = e0n + tid;
            p_i0 = tgt[eg];
            const int sg = src[eg];
            const float* rp = rel + ((size_t)p_i0 * NPART + sg) * 3;
            p_v0 = rp[0]; p_v1 = rp[1]; p_v2 = rp[2];
        } else if (tid < 2 * BM) {            // force[tgt] -> cols 0..5
            const int eg = e0n + (tid - BM);
            const float2* f2 =
                reinterpret_cast<const float2*>(force + (size_t)tgt[eg] * FDOF);
            const float2 u0 = f2[0], u1 = f2[1], u2 = f2[2];
            p_v0 = u0.x; p_v1 = u0.y; p_v2 = u1.x;
            p_f3 = u1.y; p_f4 = u2.x; p_f5 = u2.y;
        } else if (tid < 3 * BM) {            // force[src] -> cols 6..11
            const int eg = e0n + (tid - 2 * BM);
            const float2* f2 =
                reinterpret_cast<const float2*>(force + (size_t)src[eg] * FDOF);
            const float2 u0 = f2[0], u1 = f2[1], u2 = f2[2];
            p_v0 = u0.x; p_v1 = u0.y; p_v2 = u1.x;
            p_f3 = u1.y; p_f4 = u2.x; p_f5 = u2.y;
        }
    };

    auto write_x = [&](int b) {
        if (tid < BM) {                       // geometry -> cols 12..18
            const int e = tid;
            tgts[b][e] = p_i0;
            const float dist = fmaxf(
                sqrtf(p_v0 * p_v0 + p_v1 * p_v1 + p_v2 * p_v2), 1e-8f);
            const float rs = (dist - median) * (dist - median);
            bf16x4 g0 = { (__bf16)p_v0, (__bf16)p_v1,
                          (__bf16)p_v2, (__bf16)dist };
            *reinterpret_cast<bf16x4*>(&Xs[b][e][12]) = g0;   // byte 24: b64
            bf16x2 g1 = { (__bf16)rs, (__bf16)(rs * rs) };
            *reinterpret_cast<bf16x2*>(&Xs[b][e][16]) = g1;   // byte 32: b32
            Xs[b][e][18] = (__bf16)(dist - contact);
        } else if (tid < 2 * BM) {            // f_tgt -> cols 0..5
            const int e = tid - BM;
            bf16x4 g0 = { (__bf16)p_v0, (__bf16)p_v1,
                          (__bf16)p_v2, (__bf16)p_f3 };
            *reinterpret_cast<bf16x4*>(&Xs[b][e][0]) = g0;    // byte 0: b64
            bf16x2 g1 = { (__bf16)p_f4, (__bf16)p_f5 };
            *reinterpret_cast<bf16x2*>(&Xs[b][e][4]) = g1;    // byte 8: b32
        } else if (tid < 3 * BM) {            // f_src -> cols 6..11
            const int e = tid - 2 * BM;
            bf16x2 g0 = { (__bf16)p_v0, (__bf16)p_v1 };
            *reinterpret_cast<bf16x2*>(&Xs[b][e][6]) = g0;    // byte 12: b32
            bf16x4 g1 = { (__bf16)p_v2, (__bf16)p_f3,
                          (__bf16)p_f4, (__bf16)p_f5 };
            *reinterpret_cast<bf16x4*>(&Xs[b][e][8]) = g1;    // byte 16: b64
        }
    };

    // ---- prologue: stage iter-0 tile ---------------------------------------
    gather_load(blockIdx.x * BM);
    write_x(0);
    int buf = 0;

    for (int it = blockIdx.x; it < NIT; it += GRID) {
        __syncthreads();   // (A) Xs[buf]/tgts[buf] visible; Hs free (L3 done)

        // ---- layer 1: Hs(H1) = relu(W1^T X^T + b1); 8 MFMA, 4 reads --------
        #pragma unroll
        for (int et = 0; et < 4; ++et) {
            const bf16x8 xb = *reinterpret_cast<const bf16x8*>(
                &Xs[buf][et * 16 + l15][lhi * 8]);
            #pragma unroll
            for (int nb = 0; nb < 2; ++nb) {
                f32x4 acc = b1i[nb];
                acc = __builtin_amdgcn_mfma_f32_16x16x32_bf16(
                          w1f[nb], xb, acc, 0, 0, 0);
                bf16x4 hv;
                #pragma unroll
                for (int r = 0; r < 4; ++r)
                    hv[r] = (__bf16)fmaxf(acc[r], 0.0f);
                *reinterpret_cast<bf16x4*>(
                    &Hs[et * 16 + l15][(2 * w + nb) * 16 + lhi * 4]) = hv;
            }
        }
        __syncthreads();   // (B) H1 ready

        // ---- issue next tile's gathers (drain at C covered by L2 phase) ----
        const bool havenext = (it + GRID) < NIT;
        if (havenext) gather_load((it + GRID) * BM);

        // ---- layer 2: accs = W2^T H1^T + b2 (registers); 32 MFMA, 16 reads -
        f32x4 accs[4][2];
        #pragma unroll
        for (int et = 0; et < 4; ++et) {
            accs[et][0] = b2i[0];
            accs[et][1] = b2i[1];
            #pragma unroll
            for (int kt = 0; kt < 4; ++kt) {
                const bf16x8 hb = *reinterpret_cast<const bf16x8*>(
                    &Hs[et * 16 + l15][kt * 32 + lhi * 8]);
                accs[et][0] = __builtin_amdgcn_mfma_f32_16x16x32_bf16(
                                  w2f[kt][0], hb, accs[et][0], 0, 0, 0);
                accs[et][1] = __builtin_amdgcn_mfma_f32_16x16x32_bf16(
                                  w2f[kt][1], hb, accs[et][1], 0, 0, 0);
            }
        }
        __syncthreads();   // (C) all H1 reads done -> Hs reusable

        // ---- write H2 (packed b64); stage next X ---------------------------
        #pragma unroll
        for (int et = 0; et < 4; ++et)
            #pragma unroll
            for (int nb = 0; nb < 2; ++nb) {
                bf16x4 hv;
                #pragma unroll
                for (int r = 0; r < 4; ++r)
                    hv[r] = (__bf16)fmaxf(accs[et][nb][r], 0.0f);
                *reinterpret_cast<bf16x4*>(
                    &Hs[et * 16 + l15][(2 * w + nb) * 16 + lhi * 4]) = hv;
            }
        if (havenext) write_x(buf ^ 1);
        __syncthreads();   // (D) H2 ready; Xs[buf^1] staged

        // ---- layer 3: D = W3^T H2^T; rows=dof, cols=edge; 4 MFMA, 4 reads --
        f32x4 acc3 = { 0.0f, 0.0f, 0.0f, 0.0f };
        #pragma unroll
        for (int kt = 0; kt < 4; ++kt) {
            const bf16x8 hb = *reinterpret_cast<const bf16x8*>(
                &Hs[w * 16 + l15][kt * 32 + lhi * 8]);
            acc3 = __builtin_amdgcn_mfma_f32_16x16x32_bf16(
                       w3f[kt], hb, acc3, 0, 0, 0);
        }
        if (lhi < 2) {
            const int tg = tgts[buf][w * 16 + l15];
            #pragma unroll
            for (int r = 0; r < 4; ++r) {
                const int d = lhi * 4 + r;
                if (d < FDOF)
                    atomicAdd(&out[(size_t)tg * FDOF + d],
                              (acc3[r] + b3r[r]) * inv_mu);
            }
        }
        buf ^= 1;
    }
}

extern "C" void kernel_launch(void* const* d_in, const int* in_sizes, int n_in,
                              void* d_out, int out_size, void* d_ws, size_t ws_size,
                              hipStream_t stream) {
    const float* rel   = (const float*)d_in[0];
    const int*   tgt   = (const int*)d_in[1];
    const int*   src   = (const int*)d_in[2];
    const float* force = (const float*)d_in[3];
    const float* visc  = (const float*)d_in[4];
    const float* med   = (const float*)d_in[5];
    const float* con   = (const float*)d_in[6];
    const float* W1    = (const float*)d_in[7];
    const float* b1    = (const float*)d_in[8];
    const float* W2    = (const float*)d_in[9];
    const float* b2    = (const float*)d_in[10];
    const float* W3    = (const float*)d_in[11];
    const float* b3    = (const float*)d_in[12];
    float* out = (float*)d_out;

    pairvel_zero_kernel<<<(out_size + 255) / 256, 256, 0, stream>>>(out, out_size);
    pairvel_mfma_kernel<<<GRID, 256, 0, stream>>>(
        rel, tgt, src, force, visc, med, con, W1, b1, W2, b2, W3, b3, out);
}

// Round 8
// 68.030 us; speedup vs baseline: 1.3175x; 1.3175x over previous
//
#include <hip/hip_runtime.h>

#define NPART 4096
#define E_TOT 262144
#define HID   128
#define FDOF  6
#define WE    16                  // edges per wave-tile
#define NWT   (E_TOT / WE)        // 16384 wave-tiles
#define GRID  1024                // x4 waves = 4096 waves -> 4 tiles/wave exact
#define NWAVES (GRID * 4)
#define XPAD  40                  // 80 B rows (5x16) -> aligned b128 reads
#define HPAD  136                 // 272 B rows (17x16) -> aligned b128 reads

typedef __bf16 bf16x8 __attribute__((ext_vector_type(8)));
typedef __bf16 bf16x4 __attribute__((ext_vector_type(4)));
typedef __bf16 bf16x2 __attribute__((ext_vector_type(2)));
typedef float  f32x4  __attribute__((ext_vector_type(4)));

__global__ void pairvel_zero_kernel(float* __restrict__ out, int n) {
    const int i = blockIdx.x * blockDim.x + threadIdx.x;
    if (i < n) out[i] = 0.0f;
}

// Round 8: WAVE-INDEPENDENT, ZERO-BARRIER main loop. Each wave owns 16
// edges end-to-end with wave-private LDS (same-wave RAW handled by
// compiler lgkmcnt — no __syncthreads). W2 staged ONCE per block into
// LDS in fragment-major layout (32 KB, conflict-free stride-16B b128
// reads); one barrier per block lifetime. Register gather prefetch is
// now truly async (no barrier = no vmcnt(0) drain points).
// Feature order (R7-verified): f_tgt->cols 0..5, f_src->6..11,
// geom->12..18;  W1 row map ko = k<12 ? k+7 : k-12.
__global__ __launch_bounds__(256) void pairvel_mfma_kernel(
    const float* __restrict__ rel,       // [N,N,3]
    const int*   __restrict__ tgt,       // [E]
    const int*   __restrict__ src,       // [E]
    const float* __restrict__ force,     // [N,6]
    const float* __restrict__ visc,
    const float* __restrict__ medianp,
    const float* __restrict__ contactp,
    const float* __restrict__ W1,        // [19,128]
    const float* __restrict__ b1,        // [128]
    const float* __restrict__ W2,        // [128,128]
    const float* __restrict__ b2,        // [128]
    const float* __restrict__ W3,        // [128,6]
    const float* __restrict__ b3,        // [6]
    float* __restrict__ out)             // [N,6]
{
    const int tid = threadIdx.x;
    const int w   = tid >> 6;     // wave 0..3
    const int l   = tid & 63;     // lane
    const int l15 = l & 15;
    const int lhi = l >> 4;       // 0..3

    __shared__ __align__(16) __bf16 W2L[32][64][8];   // 32768 B frag-major
    __shared__ __align__(16) __bf16 Xs[4][WE][XPAD];  //  5120 B
    __shared__ __align__(16) __bf16 H1s[4][WE][HPAD]; // 17408 B
    __shared__ __align__(16) __bf16 H2s[4][WE][HPAD]; // 17408 B
    __shared__ int tgtsL[4][WE];                      //   256 B

    // ---- stage W2 into LDS, fragment-major: frag f=(kt*8+nb), lane ln ----
    #pragma unroll
    for (int i = 0; i < 8; ++i) {
        const int entry = i * 256 + tid;
        const int f  = entry >> 6;
        const int ln = entry & 63;
        const int krow = (f >> 3) * 32 + ((ln >> 4) << 3);
        const int col  = (f & 7) * 16 + (ln & 15);
        bf16x8 v;
        #pragma unroll
        for (int r = 0; r < 8; ++r)
            v[r] = (__bf16)W2[(size_t)(krow + r) * HID + col];
        *reinterpret_cast<bf16x8*>(&W2L[f][ln][0]) = v;
    }

    // ---- W1/W3 B-fragments in registers ------------------------------------
    bf16x8 w1f[8], w3f[4];
    #pragma unroll
    for (int nb = 0; nb < 8; ++nb)
        #pragma unroll
        for (int r = 0; r < 8; ++r) {
            const int k  = lhi * 8 + r;
            const int ko = (k < 12) ? k + 7 : k - 12;
            w1f[nb][r] = (k < 19) ? (__bf16)W1[ko * HID + nb * 16 + l15]
                                  : (__bf16)0.0f;
        }
    #pragma unroll
    for (int kt = 0; kt < 4; ++kt)
        #pragma unroll
        for (int r = 0; r < 8; ++r) {
            const int k = kt * 32 + lhi * 8 + r;
            w3f[kt][r] = (l15 < FDOF) ? (__bf16)W3[k * FDOF + l15]
                                      : (__bf16)0.0f;
        }

    float b1v[8], b2v[8];
    #pragma unroll
    for (int nb = 0; nb < 8; ++nb) {
        b1v[nb] = b1[nb * 16 + l15];
        b2v[nb] = b2[nb * 16 + l15];
    }
    const float b3v     = (l15 < FDOF) ? b3[l15] : 0.0f;
    const float inv_mu  = 1.0f / visc[0];
    const float median  = medianp[0];
    const float contact = contactp[0];

    // zero X pad cols 19..31 (wave-private; cols 32..39 never read)
    for (int idx = l; idx < WE * 13; idx += 64)
        Xs[w][idx / 13][19 + idx % 13] = (__bf16)0.0f;

    __syncthreads();   // the ONLY barrier: W2L visible to all waves

    // ---- per-lane prefetch state -------------------------------------------
    int   p_i0 = 0;
    float p_v0 = 0.f, p_v1 = 0.f, p_v2 = 0.f;
    float p_f3 = 0.f, p_f4 = 0.f, p_f5 = 0.f;

    auto gather_load = [&](int e0n) {
        if (l < 16) {                         // geometry, edge l
            const int eg = e0n + l;
            p_i0 = tgt[eg];
            const int sg = src[eg];
            const float* rp = rel + ((size_t)p_i0 * NPART + sg) * 3;
            p_v0 = rp[0]; p_v1 = rp[1]; p_v2 = rp[2];
        } else if (l < 32) {                  // force[tgt] -> cols 0..5
            const int eg = e0n + (l - 16);
            const float2* f2 =
                reinterpret_cast<const float2*>(force + (size_t)tgt[eg] * FDOF);
            const float2 u0 = f2[0], u1 = f2[1], u2 = f2[2];
            p_v0 = u0.x; p_v1 = u0.y; p_v2 = u1.x;
            p_f3 = u1.y; p_f4 = u2.x; p_f5 = u2.y;
        } else if (l < 48) {                  // force[src] -> cols 6..11
            const int eg = e0n + (l - 32);
            const float2* f2 =
                reinterpret_cast<const float2*>(force + (size_t)src[eg] * FDOF);
            const float2 u0 = f2[0], u1 = f2[1], u2 = f2[2];
            p_v0 = u0.x; p_v1 = u0.y; p_v2 = u1.x;
            p_f3 = u1.y; p_f4 = u2.x; p_f5 = u2.y;
        }
    };

    auto write_x = [&]() {
        if (l < 16) {                         // geom -> cols 12..18
            const int e = l;
            tgtsL[w][e] = p_i0;
            const float dist = fmaxf(
                sqrtf(p_v0 * p_v0 + p_v1 * p_v1 + p_v2 * p_v2), 1e-8f);
            const float rs = (dist - median) * (dist - median);
            bf16x4 g0 = { (__bf16)p_v0, (__bf16)p_v1,
                          (__bf16)p_v2, (__bf16)dist };
            *reinterpret_cast<bf16x4*>(&Xs[w][e][12]) = g0;   // byte 24
            bf16x2 g1 = { (__bf16)rs, (__bf16)(rs * rs) };
            *reinterpret_cast<bf16x2*>(&Xs[w][e][16]) = g1;   // byte 32
            Xs[w][e][18] = (__bf16)(dist - contact);
        } else if (l < 32) {                  // f_tgt -> cols 0..5
            const int e = l - 16;
            bf16x4 g0 = { (__bf16)p_v0, (__bf16)p_v1,
                          (__bf16)p_v2, (__bf16)p_f3 };
            *reinterpret_cast<bf16x4*>(&Xs[w][e][0]) = g0;    // byte 0
            bf16x2 g1 = { (__bf16)p_f4, (__bf16)p_f5 };
            *reinterpret_cast<bf16x2*>(&Xs[w][e][4]) = g1;    // byte 8
        } else if (l < 48) {                  // f_src -> cols 6..11
            const int e = l - 32;
            bf16x2 g0 = { (__bf16)p_v0, (__bf16)p_v1 };
            *reinterpret_cast<bf16x2*>(&Xs[w][e][6]) = g0;    // byte 12
            bf16x4 g1 = { (__bf16)p_v2, (__bf16)p_f3,
                          (__bf16)p_f4, (__bf16)p_f5 };
            *reinterpret_cast<bf16x4*>(&Xs[w][e][8]) = g1;    // byte 16
        }
    };

    const int gw = blockIdx.x * 4 + w;        // global wave id
    gather_load(gw * WE);                     // prologue loads for tile 0

    for (int t = gw; t < NWT; t += NWAVES) {
        // ---- consume prefetch regs -> X; issue next tile's gathers ---------
        write_x();
        if (t + NWAVES < NWT) gather_load((t + NWAVES) * WE);

        // ---- layer 1: H1 = relu(X @ W1 + b1); 8 MFMA -----------------------
        const bf16x8 xa = *reinterpret_cast<const bf16x8*>(
            &Xs[w][l15][lhi * 8]);
        #pragma unroll
        for (int nb = 0; nb < 8; ++nb) {
            f32x4 acc = { b1v[nb], b1v[nb], b1v[nb], b1v[nb] };
            acc = __builtin_amdgcn_mfma_f32_16x16x32_bf16(
                      xa, w1f[nb], acc, 0, 0, 0);
            #pragma unroll
            for (int j = 0; j < 4; ++j)
                H1s[w][lhi * 4 + j][nb * 16 + l15] =
                    (__bf16)fmaxf(acc[j], 0.0f);
        }

        // ---- layer 2: H2 = relu(H1 @ W2 + b2); 32 MFMA ---------------------
        bf16x8 ha[4];
        #pragma unroll
        for (int kt = 0; kt < 4; ++kt)
            ha[kt] = *reinterpret_cast<const bf16x8*>(
                &H1s[w][l15][kt * 32 + lhi * 8]);
        #pragma unroll
        for (int nb = 0; nb < 8; ++nb) {
            f32x4 acc = { b2v[nb], b2v[nb], b2v[nb], b2v[nb] };
            #pragma unroll
            for (int kt = 0; kt < 4; ++kt) {
                const bf16x8 wb = *reinterpret_cast<const bf16x8*>(
                    &W2L[kt * 8 + nb][l][0]);
                acc = __builtin_amdgcn_mfma_f32_16x16x32_bf16(
                          ha[kt], wb, acc, 0, 0, 0);
            }
            #pragma unroll
            for (int j = 0; j < 4; ++j)
                H2s[w][lhi * 4 + j][nb * 16 + l15] =
                    (__bf16)fmaxf(acc[j], 0.0f);
        }

        // ---- layer 3: vel = (H2 @ W3 + b3)/mu; 4 MFMA ----------------------
        f32x4 acc3 = { 0.0f, 0.0f, 0.0f, 0.0f };
        #pragma unroll
        for (int kt = 0; kt < 4; ++kt) {
            const bf16x8 h2a = *reinterpret_cast<const bf16x8*>(
                &H2s[w][l15][kt * 32 + lhi * 8]);
            acc3 = __builtin_amdgcn_mfma_f32_16x16x32_bf16(
                       h2a, w3f[kt], acc3, 0, 0, 0);
        }
        if (l15 < FDOF) {
            #pragma unroll
            for (int j = 0; j < 4; ++j) {
                const int e = lhi * 4 + j;
                atomicAdd(&out[(size_t)tgtsL[w][e] * FDOF + l15],
                          (acc3[j] + b3v) * inv_mu);
            }
        }
    }
}

extern "C" void kernel_launch(void* const* d_in, const int* in_sizes, int n_in,
                              void* d_out, int out_size, void* d_ws, size_t ws_size,
                              hipStream_t stream) {
    const float* rel   = (const float*)d_in[0];
    const int*   tgt   = (const int*)d_in[1];
    const int*   src   = (const int*)d_in[2];
    const float* force = (const float*)d_in[3];
    const float* visc  = (const float*)d_in[4];
    const float* med   = (const float*)d_in[5];
    const float* con   = (const float*)d_in[6];
    const float* W1    = (const float*)d_in[7];
    const float* b1    = (const float*)d_in[8];
    const float* W2    = (const float*)d_in[9];
    const float* b2    = (const float*)d_in[10];
    const float* W3    = (const float*)d_in[11];
    const float* b3    = (const float*)d_in[12];
    float* out = (float*)d_out;

    pairvel_zero_kernel<<<(out_size + 255) / 256, 256, 0, stream>>>(out, out_size);
    pairvel_mfma_kernel<<<GRID, 256, 0, stream>>>(
        rel, tgt, src, force, visc, med, con, W1, b1, W2, b2, W3, b3, out);
}